// Round 5
// baseline (210.545 us; speedup 1.0000x reference)
//
#include <hip/hip_runtime.h>
#include <hip/hip_bf16.h>

// GDGCN: out[b,c,m,t] = sum_n softmax_row(relu(t1 nv2^T))[n,m] * x[b,c,n,t]
// t1 = nv1 @ (sum_d tv[d] k[d,:,:]);  N=8192, D=32, cols = B*C*T = 192.
// R16: redundancy-1 barrier-free k_mega. R15 measurement calibrated the
// cost model: VALU-busy ~= R x 14.5us where R = #waves that redundantly
// generate the same E tile (R15: R=4 -> 57us measured, matches). Fix:
// split the block tile by M instead of cols -- wave w owns m-strips
// [mb+w*32, +32) and accumulates ALL 192 cols for them. Each wave consumes
// exactly the E it generates: R=1 total, still no LDS / no __syncthreads.
// All 4 waves read identical y/t1 addresses per slice -> L1 broadcast.
// acc = 12 coltiles x 2 mstrips x f32x4 = 96 VGPR; ~208 total -> 2 waves/
// SIMD via __launch_bounds__(256,2).
// Gen identity (HW-verified R13/R15): gen A-frag loads t1 rows permuted
// n_g(row)=8*(row>>2)+(row&3), +4 for phase B; gen 16x16x32 output concat
// {A.r0..3,B.r0..3} IS the bf16x8 B-frag of the acc 16x16x32 MFMA.
// E-pack: bit-exact RNE (pk_rne) -- v_cvt_pk_bf16_f32 is NOT RNE on
// gfx950 (R14 fail).

#define NN 8192
#define DD 32
#define TT 12
#define NSPLIT 8
#define CHUNK 1024

typedef __attribute__((ext_vector_type(8))) short bf16x8;
typedef __attribute__((ext_vector_type(4))) float f32x4;
typedef __attribute__((ext_vector_type(4))) unsigned int u32x4;

static __device__ __forceinline__ unsigned short f2bf(float f) {
  unsigned int u = __float_as_uint(f);
  u = (u + 0x7FFFu + ((u >> 16) & 1u)) >> 16;  // RNE bf16
  return (unsigned short)u;
}

static __device__ __forceinline__ float fexp2(float x) {
#if __has_builtin(__builtin_amdgcn_exp2f)
  return __builtin_amdgcn_exp2f(x);
#else
  return __builtin_exp2f(x);
#endif
}

#define MFMA32(A, B, C) __builtin_amdgcn_mfma_f32_16x16x32_bf16((A), (B), (C), 0, 0, 0)

// pack two f32 -> one u32 of 2x bf16, RNE, bit-identical to f2bf pairs
static __device__ __forceinline__ unsigned int pk_rne(float a, float b) {
  unsigned int ua = __float_as_uint(a);
  unsigned int ub = __float_as_uint(b);
  ua = ua + 0x7FFFu + ((ua >> 16) & 1u);
  ub = ub + 0x7FFFu + ((ub >> 16) & 1u);
  return (ua >> 16) | (ub & 0xFFFF0000u);  // v_lshrrev + v_and_or_b32
}

// relu -> exp2 -> RNE pack 8 f32 to bf16x8 (element e = k-slot q*8+e)
static __device__ __forceinline__ bf16x8 relu_exp2_pack(f32x4 lo, f32x4 hi) {
  u32x4 t;
  t[0] = pk_rne(fexp2(fmaxf(lo[0], 0.f)), fexp2(fmaxf(lo[1], 0.f)));
  t[1] = pk_rne(fexp2(fmaxf(lo[2], 0.f)), fexp2(fmaxf(lo[3], 0.f)));
  t[2] = pk_rne(fexp2(fmaxf(hi[0], 0.f)), fexp2(fmaxf(hi[1], 0.f)));
  t[3] = pk_rne(fexp2(fmaxf(hi[2], 0.f)), fexp2(fmaxf(hi[3], 0.f)));
  return __builtin_bit_cast(bf16x8, t);
}

// ---- fused: core = tv.k ; t1 = (nv1@core)*log2e (bf16) ; nv2 -> bf16 ; sums=0
__global__ __launch_bounds__(256) void k_prep(const float* __restrict__ nv1,
                                              const float* __restrict__ nv2,
                                              const float* __restrict__ timevec,
                                              const float* __restrict__ kk,
                                              const int* __restrict__ tind,
                                              unsigned short* __restrict__ t1b,
                                              unsigned short* __restrict__ nv2b,
                                              float* __restrict__ sums) {
  __shared__ float cs[1024];
  const int tid = threadIdx.x;
  if (tid < 128) sums[blockIdx.x * 128 + tid] = 0.f;
  const float* tv = timevec + (size_t)tind[0] * DD;
  for (int idx = tid; idx < 1024; idx += 256) {
    float acc = 0.f;
#pragma unroll
    for (int d = 0; d < DD; ++d) acc += tv[d] * kk[d * 1024 + idx];
    cs[idx] = acc;
  }
  __syncthreads();
  const int nbase = blockIdx.x * 128;
  const int f = tid & 31, sub = tid >> 5;
#pragma unroll 4
  for (int it = 0; it < 16; ++it) {
    const int n = nbase + it * 8 + sub;
    const float* nr = nv1 + (size_t)n * DD;
    float acc = 0.f;
#pragma unroll
    for (int e = 0; e < DD; ++e) acc += nr[e] * cs[e * DD + f];
    t1b[(size_t)n * DD + f] = f2bf(acc * 1.4426950408889634f);  // fold log2(e)
  }
#pragma unroll 4
  for (int it = 0; it < 16; ++it) {
    const int idx = nbase * DD + it * 256 + tid;
    nv2b[idx] = f2bf(nv2[idx]);
  }
}

// ---- sums[n] += sum_m exp2(relu(t1[n].nv2[m]))  grid (128 n, 8 m-chunks) ----
__global__ __launch_bounds__(256) void k_stats(const unsigned short* __restrict__ t1b,
                                               const unsigned short* __restrict__ nv2b,
                                               float* __restrict__ sums) {
  const int tid = threadIdx.x;
  const int w = tid >> 6, lane = tid & 63, q = lane >> 4, i16 = lane & 15;
  const int nbase = blockIdx.x * 64 + w * 16;
  bf16x8 a = *(const bf16x8*)(t1b + (size_t)(nbase + i16) * DD + q * 8);
  const f32x4 z4 = {0.f, 0.f, 0.f, 0.f};
  float s[4] = {0.f, 0.f, 0.f, 0.f};
  const int m0 = blockIdx.y * 1024;
  for (int mt = m0; mt < m0 + 1024; mt += 64) {
#pragma unroll
    for (int u = 0; u < 4; ++u) {
      bf16x8 b = *(const bf16x8*)(nv2b + (size_t)(mt + u * 16 + i16) * DD + q * 8);
      f32x4 d = __builtin_amdgcn_mfma_f32_16x16x32_bf16(a, b, z4, 0, 0, 0);
#pragma unroll
      for (int r = 0; r < 4; ++r) s[r] += fexp2(fmaxf(d[r], 0.f));
    }
  }
#pragma unroll
  for (int r = 0; r < 4; ++r)
    for (int off = 1; off < 16; off <<= 1) s[r] += __shfl_xor(s[r], off, 64);
  if (i16 == 0) {
#pragma unroll
    for (int r = 0; r < 4; ++r) atomicAdd(&sums[nbase + q * 4 + r], s[r]);
  }
}

// ---- yT[col][n] = bf16(x[bc][n][t] / sums[n]) via LDS transpose (pad 12->13) ----
__global__ __launch_bounds__(256) void k_y(const float* __restrict__ x,
                                           const float* __restrict__ sums,
                                           unsigned short* __restrict__ yT) {
  __shared__ float xs[3328];  // 256 * 13
  const int tid = threadIdx.x;
  const int n0 = blockIdx.x * 256;
  const int bc = blockIdx.y;
  const float* xp = x + (size_t)bc * NN * TT + (size_t)n0 * TT;
#pragma unroll
  for (int j = 0; j < 12; ++j) {
    const int idx = j * 256 + tid;
    xs[(idx / 12) * 13 + idx % 12] = xp[idx];
  }
  __syncthreads();
  const float rinv = 1.0f / sums[n0 + tid];
#pragma unroll
  for (int t = 0; t < 12; ++t)
    yT[(size_t)(bc * TT + t) * NN + n0 + tid] = f2bf(xs[tid * 13 + t] * rinv);
}

// ---- k_mega: part[nc][col][m] = sum_{n in chunk} E[n][m] * y[col][n] ----
// grid (64 m-superblocks of 128, 8 chunks of 1024 n); 256 thr = 4 waves.
// Wave w: m-strips [mb+w*32, +32), ALL 192 cols. Per 32-n slice: 4 gen
// MFMAs -> relu/exp2/RNE-pack (16 elems) -> 24 acc MFMAs. R=1 gen; no
// LDS; no barriers; waves share y/t1 reads via L1 (identical addresses).
__global__ __launch_bounds__(256, 2) void k_mega(const unsigned short* __restrict__ t1b,
                                                 const unsigned short* __restrict__ nv2b,
                                                 const unsigned short* __restrict__ yT,
                                                 float* __restrict__ part) {
  const int tid = threadIdx.x;
  const int w = tid >> 6, lane = tid & 63, q = lane >> 4, i16 = lane & 15;
  const int mw = blockIdx.x * 128 + w * 32;  // wave's m-base
  const int nt0 = blockIdx.y * CHUNK;

  // gen B-frags (loop-invariant): bg[ms][k=d] at col m = mw+ms*16+i16
  bf16x8 bg[2];
#pragma unroll
  for (int ms = 0; ms < 2; ++ms)
    bg[ms] = *(const bf16x8*)(nv2b + (size_t)(mw + ms * 16 + i16) * DD + q * 8);

  f32x4 acc[12][2];
#pragma unroll
  for (int c = 0; c < 12; ++c)
#pragma unroll
    for (int ms = 0; ms < 2; ++ms) acc[c][ms] = (f32x4){0.f, 0.f, 0.f, 0.f};

  // gen A-frag row permutation (HW-verified R13): A-row i16 <- t1 row
  // nt + 8*(i16>>2)+(i16&3), +4 for phase B.
  const int perm = ((i16 >> 2) << 3) | (i16 & 3);
  const unsigned short* tcur = t1b + (size_t)(nt0 + perm) * DD + q * 8;
  // y A-frags: y[col = c*16 + i16][n = nt + q*8 + e]; uniform col-tile
  // base (SGPR) + per-lane element offset (VGPR), advanced by 32/slice.
  int yoff = i16 * NN + nt0 + q * 8;

  const f32x4 z4 = {0.f, 0.f, 0.f, 0.f};

  bf16x8 alo = *(const bf16x8*)tcur;
  bf16x8 ahi = *(const bf16x8*)(tcur + 4 * DD);

  for (int it = 0; it < 32; ++it) {
    // y loads for this slice (consumed after gen+pack covers the latency)
    bf16x8 y[12];
#pragma unroll
    for (int c = 0; c < 12; ++c)
      y[c] = *(const bf16x8*)(yT + (size_t)(c * 16) * NN + yoff);

    // next-slice t1 A-frags. At it=31 this reads one tile past the chunk
    // (chunk 7: lands in nv2b region of the workspace; never consumed).
    const unsigned short* tnext = tcur + 32 * DD;
    bf16x8 alo_n = *(const bf16x8*)tnext;
    bf16x8 ahi_n = *(const bf16x8*)(tnext + 4 * DD);

    // gen E logits for this slice (independent of y loads)
    f32x4 d00 = MFMA32(alo, bg[0], z4);
    f32x4 d01 = MFMA32(ahi, bg[0], z4);
    f32x4 d10 = MFMA32(alo, bg[1], z4);
    f32x4 d11 = MFMA32(ahi, bg[1], z4);

    // pack strip 0, acc strip 0 (12 MFMAs) while packing strip 1
    bf16x8 e0 = relu_exp2_pack(d00, d01);
#pragma unroll
    for (int c = 0; c < 12; ++c) acc[c][0] = MFMA32(y[c], e0, acc[c][0]);
    bf16x8 e1 = relu_exp2_pack(d10, d11);
#pragma unroll
    for (int c = 0; c < 12; ++c) acc[c][1] = MFMA32(y[c], e1, acc[c][1]);

    alo = alo_n; ahi = ahi_n;
    tcur = tnext;
    yoff += 32;
  }

  // epilogue: lane holds col = c*16 + q*4 + r, m = mw + ms*16 + i16
  float* pp = part + (size_t)blockIdx.y * 192 * NN;
#pragma unroll
  for (int c = 0; c < 12; ++c)
#pragma unroll
    for (int ms = 0; ms < 2; ++ms) {
      const int colbase = c * 16 + q * 4;
      const int m = mw + ms * 16 + i16;
#pragma unroll
      for (int r = 0; r < 4; ++r)
        pp[(size_t)(colbase + r) * NN + m] = acc[c][ms][r];
    }
}

// ---- reduce NSPLIT partials + transpose to out[bc][m][t] (pad 12->13) ----
__global__ __launch_bounds__(256) void k_reduce(const float* __restrict__ part,
                                                float* __restrict__ out) {
  __shared__ float os[3328];  // 256 * 13
  const int tid = threadIdx.x;
  const int m0 = blockIdx.x * 256;
  const int bc = blockIdx.y;
#pragma unroll
  for (int t = 0; t < 12; ++t) {
    const int col = bc * TT + t;
    float s = 0.f;
#pragma unroll
    for (int nc = 0; nc < NSPLIT; ++nc)
      s += part[((size_t)nc * 192 + col) * NN + m0 + tid];
    os[tid * 13 + t] = s;
  }
  __syncthreads();
  float* op = out + (size_t)bc * NN * TT + (size_t)m0 * TT;
#pragma unroll
  for (int j = 0; j < 12; ++j) {
    const int idx = j * 256 + tid;
    op[idx] = os[(idx / 12) * 13 + idx % 12];
  }
}

extern "C" void kernel_launch(void* const* d_in, const int* in_sizes, int n_in,
                              void* d_out, int out_size, void* d_ws, size_t ws_size,
                              hipStream_t stream) {
  const float* x = (const float*)d_in[0];
  const float* nv1 = (const float*)d_in[1];
  const float* nv2 = (const float*)d_in[2];
  const float* tv = (const float*)d_in[3];
  const float* kk = (const float*)d_in[4];
  const int* tind = (const int*)d_in[5];
  float* out = (float*)d_out;

  char* ws = (char*)d_ws;
  unsigned short* t1b  = (unsigned short*)(ws);            //  524288 B
  unsigned short* nv2b = (unsigned short*)(ws + 524288);   //  524288 B
  float* sums          = (float*)(ws + 1048576);           //   32768 B
  unsigned short* yT   = (unsigned short*)(ws + 1081344);  // 3145728 B -> 4227072
  float* part          = (float*)(ws + 4227072);           // 50331648 B -> 54558720

  k_prep<<<64, 256, 0, stream>>>(nv1, nv2, tv, kk, tind, t1b, nv2b, sums);
  k_stats<<<dim3(128, 8), 256, 0, stream>>>(t1b, nv2b, sums);
  k_y<<<dim3(32, 16), 256, 0, stream>>>(x, sums, yT);
  k_mega<<<dim3(64, NSPLIT), 256, 0, stream>>>(t1b, nv2b, yT, part);
  k_reduce<<<dim3(32, 16), 256, 0, stream>>>(part, out);
}